// Round 2
// baseline (26172.934 us; speedup 1.0000x reference)
//
#include <hip/hip_runtime.h>
#include <hip/hip_bf16.h>

// GPT-2 small: L=12 H=12 D=768 V=50257 T=1024 B=2, HD=64
constexpr int Lc = 12, Hc = 12, Dc = 768, Vc = 50257, Tc = 1024, Bc = 2, HDc = 64;
constexpr int Mc = Bc * Tc;  // 2048 rows

// ---------------- embedding: h = wte[x] + wpe[t] ----------------
__global__ void embed_kernel(const int* __restrict__ x, const float* __restrict__ wte,
                             const float* __restrict__ wpe, float* __restrict__ h) {
    int i = blockIdx.x * blockDim.x + threadIdx.x;
    if (i >= Mc * Dc) return;
    int m = i / Dc, d = i - m * Dc;
    int t = m % Tc;
    int tok = x[m];
    h[i] = wte[(size_t)tok * Dc + d] + wpe[(size_t)t * Dc + d];
}

// ---------------- layernorm ----------------
__global__ __launch_bounds__(256) void ln_kernel(const float* __restrict__ x,
                                                 const float* __restrict__ w,
                                                 const float* __restrict__ b,
                                                 float* __restrict__ out) {
    int row = blockIdx.x;
    const float* xr = x + (size_t)row * Dc;
    float vals[3];
    float s = 0.f, sq = 0.f;
#pragma unroll
    for (int i = 0; i < 3; i++) {
        float v = xr[threadIdx.x + i * 256];
        vals[i] = v;
        s += v;
        sq += v * v;
    }
    __shared__ float red[256], red2[256];
    red[threadIdx.x] = s;
    red2[threadIdx.x] = sq;
    __syncthreads();
    for (int st = 128; st > 0; st >>= 1) {
        if (threadIdx.x < st) {
            red[threadIdx.x] += red[threadIdx.x + st];
            red2[threadIdx.x] += red2[threadIdx.x + st];
        }
        __syncthreads();
    }
    float mean = red[0] * (1.f / Dc);
    float var = red2[0] * (1.f / Dc) - mean * mean;
    float rstd = rsqrtf(var + 1e-5f);
#pragma unroll
    for (int i = 0; i < 3; i++) {
        int d = threadIdx.x + i * 256;
        out[(size_t)row * Dc + d] = (vals[i] - mean) * rstd * w[d] + b[d];
    }
}

// ---------------- generic tiled GEMM: C[M,N] = A[M,K] @ B + epilogue ----------------
// EPI: 0 = bias only, 1 = bias + residual add, 2 = bias + tanh-GELU
// BT:  false: B is [K,N] row-major. true: B is [N,K] row-major (lm_head vs wte^T)
template <int EPI, bool BT>
__global__ __launch_bounds__(256) void gemm_kernel(const float* __restrict__ A,
                                                   const float* __restrict__ Bw,
                                                   const float* __restrict__ bias,
                                                   const float* __restrict__ resid,
                                                   float* __restrict__ Cout,
                                                   int M, int N, int K) {
    __shared__ float As[16][65];
    __shared__ float Bs[16][65];
    int tid = threadIdx.x;
    int tx = tid & 15, ty = tid >> 4;
    int m0 = blockIdx.y * 64, n0 = blockIdx.x * 64;
    float acc[4][4] = {};

    for (int k0 = 0; k0 < K; k0 += 16) {
        // A tile 64x16 (k fastest -> coalesced)
#pragma unroll
        for (int i = 0; i < 4; i++) {
            int e = tid + i * 256;
            int r = e >> 4, kk = e & 15;
            As[kk][r] = A[(size_t)(m0 + r) * K + k0 + kk];
        }
        // B tile 16x64
#pragma unroll
        for (int i = 0; i < 4; i++) {
            int e = tid + i * 256;
            if (BT) {
                int c = e >> 4, kk = e & 15;
                int n = n0 + c;
                Bs[kk][c] = (n < N) ? Bw[(size_t)n * K + k0 + kk] : 0.f;
            } else {
                int kk = e >> 6, c = e & 63;
                int n = n0 + c;
                Bs[kk][c] = (n < N) ? Bw[(size_t)(k0 + kk) * N + n] : 0.f;
            }
        }
        __syncthreads();
#pragma unroll
        for (int kk = 0; kk < 16; kk++) {
            float a4[4], b4[4];
#pragma unroll
            for (int i = 0; i < 4; i++) a4[i] = As[kk][ty * 4 + i];
#pragma unroll
            for (int j = 0; j < 4; j++) b4[j] = Bs[kk][tx * 4 + j];
#pragma unroll
            for (int i = 0; i < 4; i++)
#pragma unroll
                for (int j = 0; j < 4; j++) acc[i][j] = fmaf(a4[i], b4[j], acc[i][j]);
        }
        __syncthreads();
    }

#pragma unroll
    for (int i = 0; i < 4; i++) {
        int row = m0 + ty * 4 + i;
#pragma unroll
        for (int j = 0; j < 4; j++) {
            int col = n0 + tx * 4 + j;
            if (col >= N) continue;
            float v = acc[i][j];
            if (bias) v += bias[col];
            if (EPI == 1) v += resid[(size_t)row * N + col];
            if (EPI == 2) {
                float x3 = v * v * v;
                v = 0.5f * v * (1.f + tanhf(0.7978845608028654f * (v + 0.044715f * x3)));
            }
            Cout[(size_t)row * N + col] = v;
        }
    }
}

// ---------------- causal attention, one block per (q, head, batch) ----------------
__global__ __launch_bounds__(256) void attn_kernel(const float* __restrict__ qkv,
                                                   float* __restrict__ y) {
    int q = blockIdx.x, hh = blockIdx.y, b = blockIdx.z;
    __shared__ float sc[Tc];
    __shared__ float qv[HDc];
    __shared__ float part[4][HDc];
    __shared__ float red[256];
    int tid = threadIdx.x;
    int lane = tid & 63, w = tid >> 6;
    const float scale = 0.125f;  // 1/sqrt(64)

    size_t qrow = ((size_t)b * Tc + q) * (3 * Dc) + hh * HDc;
    if (tid < HDc) qv[tid] = qkv[qrow + tid] * scale;
    __syncthreads();

    for (int j = w; j <= q; j += 4) {
        const float* kr = qkv + ((size_t)b * Tc + j) * (3 * Dc) + Dc + hh * HDc;
        float p = qv[lane] * kr[lane];
#pragma unroll
        for (int o = 32; o > 0; o >>= 1) p += __shfl_xor(p, o, 64);
        if (lane == 0) sc[j] = p;
    }
    __syncthreads();

    float mx = -1e30f;
    for (int j = tid; j <= q; j += 256) mx = fmaxf(mx, sc[j]);
    red[tid] = mx;
    __syncthreads();
    for (int st = 128; st > 0; st >>= 1) {
        if (tid < st) red[tid] = fmaxf(red[tid], red[tid + st]);
        __syncthreads();
    }
    mx = red[0];
    __syncthreads();
    float sum = 0.f;
    for (int j = tid; j <= q; j += 256) {
        float p = expf(sc[j] - mx);
        sc[j] = p;
        sum += p;
    }
    red[tid] = sum;
    __syncthreads();
    for (int st = 128; st > 0; st >>= 1) {
        if (tid < st) red[tid] += red[tid + st];
        __syncthreads();
    }
    float denom = red[0];
    __syncthreads();

    float acc = 0.f;
    for (int j = w; j <= q; j += 4) {
        const float* vr = qkv + ((size_t)b * Tc + j) * (3 * Dc) + 2 * Dc + hh * HDc;
        acc += sc[j] * vr[lane];
    }
    part[w][lane] = acc;
    __syncthreads();
    if (tid < HDc) {
        float ysum = part[0][tid] + part[1][tid] + part[2][tid] + part[3][tid];
        y[((size_t)b * Tc + q) * Dc + hh * HDc + tid] = ysum / denom;
    }
}

extern "C" void kernel_launch(void* const* d_in, const int* in_sizes, int n_in,
                              void* d_out, int out_size, void* d_ws, size_t ws_size,
                              hipStream_t stream) {
    const int* x = (const int*)d_in[0];
    const float* wte = (const float*)d_in[1];
    const float* wpe = (const float*)d_in[2];
    const float* ln1w = (const float*)d_in[3];
    const float* ln1b = (const float*)d_in[4];
    const float* qkvw = (const float*)d_in[5];
    const float* qkvb = (const float*)d_in[6];
    const float* projw = (const float*)d_in[7];
    const float* projb = (const float*)d_in[8];
    const float* ln2w = (const float*)d_in[9];
    const float* ln2b = (const float*)d_in[10];
    const float* fcw = (const float*)d_in[11];
    const float* fcb = (const float*)d_in[12];
    const float* fcpw = (const float*)d_in[13];
    const float* fcpb = (const float*)d_in[14];
    const float* lnfw = (const float*)d_in[15];
    const float* lnfb = (const float*)d_in[16];

    // f32 workspace layout (~57 MB)
    float* h = (float*)d_ws;                 // [M][D]
    float* a = h + (size_t)Mc * Dc;          // [M][D]
    float* qkv = a + (size_t)Mc * Dc;        // [M][3D]
    float* mlp = qkv + (size_t)Mc * 3 * Dc;  // [M][4D]

    embed_kernel<<<(Mc * Dc + 255) / 256, 256, 0, stream>>>(x, wte, wpe, h);

    for (int l = 0; l < Lc; l++) {
        ln_kernel<<<Mc, 256, 0, stream>>>(h, ln1w + (size_t)l * Dc, ln1b + (size_t)l * Dc, a);
        gemm_kernel<0, false><<<dim3(3 * Dc / 64, Mc / 64), 256, 0, stream>>>(
            a, qkvw + (size_t)l * Dc * 3 * Dc, qkvb + (size_t)l * 3 * Dc, nullptr, qkv,
            Mc, 3 * Dc, Dc);
        attn_kernel<<<dim3(Tc, Hc, Bc), 256, 0, stream>>>(qkv, a);
        gemm_kernel<1, false><<<dim3(Dc / 64, Mc / 64), 256, 0, stream>>>(
            a, projw + (size_t)l * Dc * Dc, projb + (size_t)l * Dc, h, h, Mc, Dc, Dc);
        ln_kernel<<<Mc, 256, 0, stream>>>(h, ln2w + (size_t)l * Dc, ln2b + (size_t)l * Dc, a);
        gemm_kernel<2, false><<<dim3(4 * Dc / 64, Mc / 64), 256, 0, stream>>>(
            a, fcw + (size_t)l * Dc * 4 * Dc, fcb + (size_t)l * 4 * Dc, nullptr, mlp,
            Mc, 4 * Dc, Dc);
        gemm_kernel<1, false><<<dim3(Dc / 64, Mc / 64), 256, 0, stream>>>(
            mlp, fcpw + (size_t)l * 4 * Dc * Dc, fcpb + (size_t)l * Dc, h, h, Mc, Dc, 4 * Dc);
    }

    ln_kernel<<<Mc, 256, 0, stream>>>(h, lnfw, lnfb, a);
    gemm_kernel<0, true><<<dim3((Vc + 63) / 64, Mc / 64), 256, 0, stream>>>(
        a, wte, nullptr, nullptr, (float*)d_out, Mc, Vc, Dc);
}

// Round 3
// 14570.897 us; speedup vs baseline: 1.7962x; 1.7962x over previous
//
#include <hip/hip_runtime.h>
#include <hip/hip_bf16.h>

typedef __hip_bfloat16 hbf16;
using bf16x8 = __attribute__((ext_vector_type(8))) __bf16;
using f32x4 = __attribute__((ext_vector_type(4))) float;

// GPT-2 small: L=12 H=12 D=768 V=50257 T=1024 B=2, HD=64
constexpr int Lc = 12, Hc = 12, Dc = 768, Vc = 50257, Tc = 1024, Bc = 2, HDc = 64;
constexpr int Mc = Bc * Tc;       // 2048 rows
constexpr int Vpad = 50304;       // 393*128, zero-padded vocab

#define GLD16(gp, lp)                                               \
    __builtin_amdgcn_global_load_lds(                               \
        (__attribute__((address_space(1))) void*)(void*)(gp),       \
        (__attribute__((address_space(3))) void*)(void*)(lp), 16, 0, 0)

// ---------------- embedding: h = wte[x] + wpe[t] (f32) ----------------
__global__ void embed_kernel(const int* __restrict__ x, const float* __restrict__ wte,
                             const float* __restrict__ wpe, float* __restrict__ h) {
    int i = blockIdx.x * blockDim.x + threadIdx.x;
    if (i >= Mc * Dc) return;
    int m = i / Dc, d = i - m * Dc;
    int t = m % Tc;
    int tok = x[m];
    h[i] = wte[(size_t)tok * Dc + d] + wpe[(size_t)t * Dc + d];
}

// ---------------- layernorm: f32 in -> bf16 out ----------------
__global__ __launch_bounds__(256) void ln_kernel(const float* __restrict__ x,
                                                 const float* __restrict__ w,
                                                 const float* __restrict__ b,
                                                 hbf16* __restrict__ out) {
    int row = blockIdx.x;
    const float* xr = x + (size_t)row * Dc;
    float vals[3];
    float s = 0.f, sq = 0.f;
#pragma unroll
    for (int i = 0; i < 3; i++) {
        float v = xr[threadIdx.x + i * 256];
        vals[i] = v;
        s += v;
        sq += v * v;
    }
    __shared__ float red[256], red2[256];
    red[threadIdx.x] = s;
    red2[threadIdx.x] = sq;
    __syncthreads();
    for (int st = 128; st > 0; st >>= 1) {
        if (threadIdx.x < st) {
            red[threadIdx.x] += red[threadIdx.x + st];
            red2[threadIdx.x] += red2[threadIdx.x + st];
        }
        __syncthreads();
    }
    float mean = red[0] * (1.f / Dc);
    float var = red2[0] * (1.f / Dc) - mean * mean;
    float rstd = rsqrtf(var + 1e-5f);
#pragma unroll
    for (int i = 0; i < 3; i++) {
        int d = threadIdx.x + i * 256;
        out[(size_t)row * Dc + d] =
            __float2bfloat16((vals[i] - mean) * rstd * w[d] + b[d]);
    }
}

// ---------------- weight transpose+convert: W[K][N] f32 -> Wt[N][K] bf16 ----------
__global__ __launch_bounds__(256) void transpose_convert(const float* __restrict__ W,
                                                         hbf16* __restrict__ Wt,
                                                         int K, int N) {
    __shared__ float tile[32][33];
    int n0 = blockIdx.x * 32, k0 = blockIdx.y * 32;
    int tx = threadIdx.x, ty = threadIdx.y;  // (32,8)
#pragma unroll
    for (int i = 0; i < 4; i++) {
        int r = ty + i * 8;
        tile[r][tx] = W[(size_t)(k0 + r) * N + n0 + tx];
    }
    __syncthreads();
#pragma unroll
    for (int i = 0; i < 4; i++) {
        int r = ty + i * 8;
        Wt[(size_t)(n0 + r) * K + k0 + tx] = __float2bfloat16(tile[tx][r]);
    }
}

// ---------------- wte f32 [V][D] -> bf16 [Vpad][D] (zero pad) ----------------
__global__ void convert_wte(const float* __restrict__ wte, hbf16* __restrict__ out) {
    size_t i4 = ((size_t)blockIdx.x * 256 + threadIdx.x) * 4;
    if (i4 >= (size_t)Vpad * Dc) return;
    if (i4 < (size_t)Vc * Dc) {
#pragma unroll
        for (int j = 0; j < 4; j++) out[i4 + j] = __float2bfloat16(wte[i4 + j]);
    } else {
#pragma unroll
        for (int j = 0; j < 4; j++) out[i4 + j] = __float2bfloat16(0.f);
    }
}

// ---------------- MFMA GEMM: C[M,N] = A[M,K](bf16) @ Bt[N,K](bf16)^T + epilogue ----
// EPI: 0 = +bias, 1 = +bias +f32 residual, 2 = +bias + tanh-GELU
// OUTBF: true -> bf16 out, false -> f32 out
// grid: (Npad/128, M/128), 256 threads (4 waves, 2x2)
template <int EPI, bool OUTBF>
__global__ __launch_bounds__(256) void mm_kernel(const hbf16* __restrict__ A,
                                                 const hbf16* __restrict__ Bt,
                                                 const float* __restrict__ bias,
                                                 const float* __restrict__ resid,
                                                 void* __restrict__ Cout,
                                                 int M, int N, int K) {
    __shared__ __bf16 As[128 * 32];
    __shared__ __bf16 Bs[128 * 32];
    int tid = threadIdx.x;
    int l = tid & 63, w = tid >> 6;
    int wr = w >> 1, wc = w & 1;
    int m0 = blockIdx.y * 128, n0 = blockIdx.x * 128;

    // staging: each wave covers rows [w*32, w*32+32) of the 128x32 tile via 2 issues
    int off0 = w * 2048 + l * 16;           // byte offset in 8KB tile, issue 0
    int r0 = off0 >> 6, c0 = (off0 & 63) >> 1;
    int off1 = off0 + 1024;
    int r1 = off1 >> 6, c1 = (off1 & 63) >> 1;

    const hbf16* pA0 = A + (size_t)(m0 + r0) * K + c0;
    const hbf16* pA1 = A + (size_t)(m0 + r1) * K + c1;
    const hbf16* pB0 = Bt + (size_t)(n0 + r0) * K + c0;
    const hbf16* pB1 = Bt + (size_t)(n0 + r1) * K + c1;
    __bf16* lA0 = As + w * 1024;   // bf16 units: w*2048B
    __bf16* lA1 = As + w * 1024 + 512;
    __bf16* lB0 = Bs + w * 1024;
    __bf16* lB1 = Bs + w * 1024 + 512;

    int lr = l & 15, lg = l >> 4;
    int aoff[4], boff[4];
#pragma unroll
    for (int m = 0; m < 4; m++) aoff[m] = (wr * 64 + m * 16 + lr) * 32 + lg * 8;
#pragma unroll
    for (int n = 0; n < 4; n++) boff[n] = (wc * 64 + n * 16 + lr) * 32 + lg * 8;

    f32x4 acc[4][4] = {};

    for (int k0 = 0; k0 < K; k0 += 32) {
        GLD16(pA0, lA0);
        GLD16(pA1, lA1);
        GLD16(pB0, lB0);
        GLD16(pB1, lB1);
        pA0 += 32; pA1 += 32; pB0 += 32; pB1 += 32;
        __syncthreads();
        bf16x8 af[4], bf[4];
#pragma unroll
        for (int m = 0; m < 4; m++) af[m] = *(const bf16x8*)&As[aoff[m]];
#pragma unroll
        for (int n = 0; n < 4; n++) bf[n] = *(const bf16x8*)&Bs[boff[n]];
#pragma unroll
        for (int m = 0; m < 4; m++)
#pragma unroll
            for (int n = 0; n < 4; n++)
                acc[m][n] = __builtin_amdgcn_mfma_f32_16x16x32_bf16(af[m], bf[n], acc[m][n], 0, 0, 0);
        __syncthreads();
    }

    // epilogue: C/D layout col = lane&15, row = (lane>>4)*4 + reg
#pragma unroll
    for (int n = 0; n < 4; n++) {
        int col = n0 + wc * 64 + n * 16 + lr;
        bool cok = col < N;
        float bv = (bias && cok) ? bias[col] : 0.f;
#pragma unroll
        for (int m = 0; m < 4; m++) {
#pragma unroll
            for (int r = 0; r < 4; r++) {
                int row = m0 + wr * 64 + m * 16 + lg * 4 + r;
                if (!cok) continue;
                float v = acc[m][n][r] + bv;
                if (EPI == 1) v += resid[(size_t)row * N + col];
                if (EPI == 2) {
                    float x3 = v * v * v;
                    v = 0.5f * v * (1.f + tanhf(0.7978845608028654f * (v + 0.044715f * x3)));
                }
                if (OUTBF)
                    ((hbf16*)Cout)[(size_t)row * N + col] = __float2bfloat16(v);
                else
                    ((float*)Cout)[(size_t)row * N + col] = v;
            }
        }
    }
}

// ---------------- causal attention (f32 math, bf16 out) ----------------
__global__ __launch_bounds__(256) void attn_kernel(const float* __restrict__ qkv,
                                                   hbf16* __restrict__ y) {
    int q = blockIdx.x, hh = blockIdx.y, b = blockIdx.z;
    __shared__ float sc[Tc];
    __shared__ float qv[HDc];
    __shared__ float part[4][HDc];
    __shared__ float red[256];
    int tid = threadIdx.x;
    int lane = tid & 63, w = tid >> 6;
    const float scale = 0.125f;

    size_t qrow = ((size_t)b * Tc + q) * (3 * Dc) + hh * HDc;
    if (tid < HDc) qv[tid] = qkv[qrow + tid] * scale;
    __syncthreads();

    for (int j = w; j <= q; j += 4) {
        const float* kr = qkv + ((size_t)b * Tc + j) * (3 * Dc) + Dc + hh * HDc;
        float p = qv[lane] * kr[lane];
#pragma unroll
        for (int o = 32; o > 0; o >>= 1) p += __shfl_xor(p, o, 64);
        if (lane == 0) sc[j] = p;
    }
    __syncthreads();

    float mx = -1e30f;
    for (int j = tid; j <= q; j += 256) mx = fmaxf(mx, sc[j]);
    red[tid] = mx;
    __syncthreads();
    for (int st = 128; st > 0; st >>= 1) {
        if (tid < st) red[tid] = fmaxf(red[tid], red[tid + st]);
        __syncthreads();
    }
    mx = red[0];
    __syncthreads();
    float sum = 0.f;
    for (int j = tid; j <= q; j += 256) {
        float p = expf(sc[j] - mx);
        sc[j] = p;
        sum += p;
    }
    red[tid] = sum;
    __syncthreads();
    for (int st = 128; st > 0; st >>= 1) {
        if (tid < st) red[tid] += red[tid + st];
        __syncthreads();
    }
    float denom = red[0];
    __syncthreads();

    float acc = 0.f;
    for (int j = w; j <= q; j += 4) {
        const float* vr = qkv + ((size_t)b * Tc + j) * (3 * Dc) + 2 * Dc + hh * HDc;
        acc += sc[j] * vr[lane];
    }
    part[w][lane] = acc;
    __syncthreads();
    if (tid < HDc) {
        float ysum = part[0][tid] + part[1][tid] + part[2][tid] + part[3][tid];
        y[((size_t)b * Tc + q) * Dc + hh * HDc + tid] = __float2bfloat16(ysum / denom);
    }
}

extern "C" void kernel_launch(void* const* d_in, const int* in_sizes, int n_in,
                              void* d_out, int out_size, void* d_ws, size_t ws_size,
                              hipStream_t stream) {
    const int* x = (const int*)d_in[0];
    const float* wte = (const float*)d_in[1];
    const float* wpe = (const float*)d_in[2];
    const float* ln1w = (const float*)d_in[3];
    const float* ln1b = (const float*)d_in[4];
    const float* qkvw = (const float*)d_in[5];
    const float* qkvb = (const float*)d_in[6];
    const float* projw = (const float*)d_in[7];
    const float* projb = (const float*)d_in[8];
    const float* ln2w = (const float*)d_in[9];
    const float* ln2b = (const float*)d_in[10];
    const float* fcw = (const float*)d_in[11];
    const float* fcb = (const float*)d_in[12];
    const float* fcpw = (const float*)d_in[13];
    const float* fcpb = (const float*)d_in[14];
    const float* lnfw = (const float*)d_in[15];
    const float* lnfb = (const float*)d_in[16];

    // workspace layout (all 16B-aligned)
    char* p = (char*)d_ws;
    float* h = (float*)p;      p += (size_t)Mc * Dc * 4;        // f32 [M][D]
    float* qkv = (float*)p;    p += (size_t)Mc * 3 * Dc * 4;    // f32 [M][3D]
    hbf16* a = (hbf16*)p;      p += (size_t)Mc * Dc * 2;        // bf16 [M][D]
    hbf16* y = (hbf16*)p;      p += (size_t)Mc * Dc * 2;        // bf16 [M][D]
    hbf16* mlp = (hbf16*)p;    p += (size_t)Mc * 4 * Dc * 2;    // bf16 [M][4D]
    hbf16* wq_t = (hbf16*)p;   p += (size_t)3 * Dc * Dc * 2;    // [2304][768]
    hbf16* wp_t = (hbf16*)p;   p += (size_t)Dc * Dc * 2;        // [768][768]
    hbf16* wf_t = (hbf16*)p;   p += (size_t)4 * Dc * Dc * 2;    // [3072][768]
    hbf16* wfp_t = (hbf16*)p;  p += (size_t)4 * Dc * Dc * 2;    // [768][3072]
    hbf16* wte_b = (hbf16*)p;  p += (size_t)Vpad * Dc * 2;      // [50304][768]

    embed_kernel<<<(Mc * Dc + 255) / 256, 256, 0, stream>>>(x, wte, wpe, h);
    convert_wte<<<((size_t)Vpad * Dc / 4 + 255) / 256, 256, 0, stream>>>(wte, wte_b);

    dim3 tb(32, 8);
    for (int l = 0; l < Lc; l++) {
        transpose_convert<<<dim3(3 * Dc / 32, Dc / 32), tb, 0, stream>>>(
            qkvw + (size_t)l * Dc * 3 * Dc, wq_t, Dc, 3 * Dc);
        transpose_convert<<<dim3(Dc / 32, Dc / 32), tb, 0, stream>>>(
            projw + (size_t)l * Dc * Dc, wp_t, Dc, Dc);
        transpose_convert<<<dim3(4 * Dc / 32, Dc / 32), tb, 0, stream>>>(
            fcw + (size_t)l * Dc * 4 * Dc, wf_t, Dc, 4 * Dc);
        transpose_convert<<<dim3(Dc / 32, 4 * Dc / 32), tb, 0, stream>>>(
            fcpw + (size_t)l * 4 * Dc * Dc, wfp_t, 4 * Dc, Dc);

        ln_kernel<<<Mc, 256, 0, stream>>>(h, ln1w + (size_t)l * Dc, ln1b + (size_t)l * Dc, a);
        mm_kernel<0, false><<<dim3(3 * Dc / 128, Mc / 128), 256, 0, stream>>>(
            a, wq_t, qkvb + (size_t)l * 3 * Dc, nullptr, qkv, Mc, 3 * Dc, Dc);
        attn_kernel<<<dim3(Tc, Hc, Bc), 256, 0, stream>>>(qkv, y);
        mm_kernel<1, false><<<dim3(Dc / 128, Mc / 128), 256, 0, stream>>>(
            y, wp_t, projb + (size_t)l * Dc, h, h, Mc, Dc, Dc);
        ln_kernel<<<Mc, 256, 0, stream>>>(h, ln2w + (size_t)l * Dc, ln2b + (size_t)l * Dc, a);
        mm_kernel<2, true><<<dim3(4 * Dc / 128, Mc / 128), 256, 0, stream>>>(
            a, wf_t, fcb + (size_t)l * 4 * Dc, nullptr, mlp, Mc, 4 * Dc, Dc);
        mm_kernel<1, false><<<dim3(Dc / 128, Mc / 128), 256, 0, stream>>>(
            mlp, wfp_t, fcpb + (size_t)l * Dc, h, h, Mc, Dc, 4 * Dc);
    }

    ln_kernel<<<Mc, 256, 0, stream>>>(h, lnfw, lnfb, a);
    mm_kernel<0, false><<<dim3(Vpad / 128, Mc / 128), 256, 0, stream>>>(
        a, wte_b, nullptr, nullptr, (float*)d_out, Mc, Vc, Dc);
}

// Round 4
// 3102.746 us; speedup vs baseline: 8.4354x; 4.6961x over previous
//
#include <hip/hip_runtime.h>
#include <hip/hip_bf16.h>

typedef __hip_bfloat16 hbf16;
using bf16x8 = __attribute__((ext_vector_type(8))) __bf16;
using f32x4 = __attribute__((ext_vector_type(4))) float;

// GPT-2 small: L=12 H=12 D=768 V=50257 T=1024 B=2, HD=64
constexpr int Lc = 12, Hc = 12, Dc = 768, Vc = 50257, Tc = 1024, Bc = 2, HDc = 64;
constexpr int Mc = Bc * Tc;  // 2048 rows
constexpr int Vpad = 50304;  // 393*128, zero-padded vocab

#define GLD16(gp, lp)                                               \
    __builtin_amdgcn_global_load_lds(                               \
        (__attribute__((address_space(1))) void*)(void*)(gp),       \
        (__attribute__((address_space(3))) void*)(void*)(lp), 16, 0, 0)

// ---------------- embedding: h = wte[x] + wpe[t] (f32) ----------------
__global__ void embed_kernel(const int* __restrict__ x, const float* __restrict__ wte,
                             const float* __restrict__ wpe, float* __restrict__ h) {
    int i = blockIdx.x * blockDim.x + threadIdx.x;
    if (i >= Mc * Dc) return;
    int m = i / Dc, d = i - m * Dc;
    int t = m % Tc;
    int tok = x[m];
    h[i] = wte[(size_t)tok * Dc + d] + wpe[(size_t)t * Dc + d];
}

// ---------------- layernorm: f32 in -> bf16 out ----------------
__global__ __launch_bounds__(256) void ln_kernel(const float* __restrict__ x,
                                                 const float* __restrict__ w,
                                                 const float* __restrict__ b,
                                                 hbf16* __restrict__ out) {
    int row = blockIdx.x;
    const float* xr = x + (size_t)row * Dc;
    float vals[3];
    float s = 0.f, sq = 0.f;
#pragma unroll
    for (int i = 0; i < 3; i++) {
        float v = xr[threadIdx.x + i * 256];
        vals[i] = v;
        s += v;
        sq += v * v;
    }
    __shared__ float red[256], red2[256];
    red[threadIdx.x] = s;
    red2[threadIdx.x] = sq;
    __syncthreads();
    for (int st = 128; st > 0; st >>= 1) {
        if (threadIdx.x < st) {
            red[threadIdx.x] += red[threadIdx.x + st];
            red2[threadIdx.x] += red2[threadIdx.x + st];
        }
        __syncthreads();
    }
    float mean = red[0] * (1.f / Dc);
    float var = red2[0] * (1.f / Dc) - mean * mean;
    float rstd = rsqrtf(var + 1e-5f);
#pragma unroll
    for (int i = 0; i < 3; i++) {
        int d = threadIdx.x + i * 256;
        out[(size_t)row * Dc + d] =
            __float2bfloat16((vals[i] - mean) * rstd * w[d] + b[d]);
    }
}

// ---------------- weight transpose+convert: W[K][N] f32 -> Wt[N][K] bf16 ----------
__global__ __launch_bounds__(256) void transpose_convert(const float* __restrict__ W,
                                                         hbf16* __restrict__ Wt,
                                                         int K, int N) {
    __shared__ float tile[32][33];
    int n0 = blockIdx.x * 32, k0 = blockIdx.y * 32;
    int tx = threadIdx.x, ty = threadIdx.y;  // (32,8)
#pragma unroll
    for (int i = 0; i < 4; i++) {
        int r = ty + i * 8;
        tile[r][tx] = W[(size_t)(k0 + r) * N + n0 + tx];
    }
    __syncthreads();
#pragma unroll
    for (int i = 0; i < 4; i++) {
        int r = ty + i * 8;
        Wt[(size_t)(n0 + r) * K + k0 + tx] = __float2bfloat16(tile[tx][r]);
    }
}

// ---------------- wte f32 [V][D] -> bf16 [Vpad][D] (zero pad) ----------------
__global__ void convert_wte(const float* __restrict__ wte, hbf16* __restrict__ out) {
    size_t i4 = ((size_t)blockIdx.x * 256 + threadIdx.x) * 4;
    if (i4 >= (size_t)Vpad * Dc) return;
    if (i4 < (size_t)Vc * Dc) {
#pragma unroll
        for (int j = 0; j < 4; j++) out[i4 + j] = __float2bfloat16(wte[i4 + j]);
    } else {
#pragma unroll
        for (int j = 0; j < 4; j++) out[i4 + j] = __float2bfloat16(0.f);
    }
}

// ---------------- MFMA GEMM: C[M,N] = A[M,K](bf16) @ Bt[N,K](bf16)^T + epilogue ----
// EPI: 0 = +bias, 1 = +bias +f32 residual, 2 = +bias + tanh-GELU
template <int EPI, bool OUTBF>
__global__ __launch_bounds__(256) void mm_kernel(const hbf16* __restrict__ A,
                                                 const hbf16* __restrict__ Bt,
                                                 const float* __restrict__ bias,
                                                 const float* __restrict__ resid,
                                                 void* __restrict__ Cout,
                                                 int M, int N, int K) {
    __shared__ __bf16 As[128 * 32];
    __shared__ __bf16 Bs[128 * 32];
    int tid = threadIdx.x;
    int l = tid & 63, w = tid >> 6;
    int wr = w >> 1, wc = w & 1;
    int m0 = blockIdx.y * 128, n0 = blockIdx.x * 128;

    int off0 = w * 2048 + l * 16;  // byte offset in 8KB tile
    int r0 = off0 >> 6, c0 = (off0 & 63) >> 1;
    int off1 = off0 + 1024;
    int r1 = off1 >> 6, c1 = (off1 & 63) >> 1;

    const hbf16* pA0 = A + (size_t)(m0 + r0) * K + c0;
    const hbf16* pA1 = A + (size_t)(m0 + r1) * K + c1;
    const hbf16* pB0 = Bt + (size_t)(n0 + r0) * K + c0;
    const hbf16* pB1 = Bt + (size_t)(n0 + r1) * K + c1;
    __bf16* lA0 = As + w * 1024;
    __bf16* lA1 = As + w * 1024 + 512;
    __bf16* lB0 = Bs + w * 1024;
    __bf16* lB1 = Bs + w * 1024 + 512;

    int lr = l & 15, lg = l >> 4;
    int aoff[4], boff[4];
#pragma unroll
    for (int m = 0; m < 4; m++) aoff[m] = (wr * 64 + m * 16 + lr) * 32 + lg * 8;
#pragma unroll
    for (int n = 0; n < 4; n++) boff[n] = (wc * 64 + n * 16 + lr) * 32 + lg * 8;

    f32x4 acc[4][4] = {};

    for (int k0 = 0; k0 < K; k0 += 32) {
        GLD16(pA0, lA0);
        GLD16(pA1, lA1);
        GLD16(pB0, lB0);
        GLD16(pB1, lB1);
        pA0 += 32; pA1 += 32; pB0 += 32; pB1 += 32;
        __syncthreads();
        bf16x8 af[4], bfr[4];
#pragma unroll
        for (int m = 0; m < 4; m++) af[m] = *(const bf16x8*)&As[aoff[m]];
#pragma unroll
        for (int n = 0; n < 4; n++) bfr[n] = *(const bf16x8*)&Bs[boff[n]];
#pragma unroll
        for (int m = 0; m < 4; m++)
#pragma unroll
            for (int n = 0; n < 4; n++)
                acc[m][n] = __builtin_amdgcn_mfma_f32_16x16x32_bf16(af[m], bfr[n], acc[m][n], 0, 0, 0);
        __syncthreads();
    }

#pragma unroll
    for (int n = 0; n < 4; n++) {
        int col = n0 + wc * 64 + n * 16 + lr;
        bool cok = col < N;
        float bv = (bias && cok) ? bias[col] : 0.f;
#pragma unroll
        for (int m = 0; m < 4; m++) {
#pragma unroll
            for (int r = 0; r < 4; r++) {
                int row = m0 + wr * 64 + m * 16 + lg * 4 + r;
                if (!cok) continue;
                float v = acc[m][n][r] + bv;
                if (EPI == 1) v += resid[(size_t)row * N + col];
                if (EPI == 2) {
                    float x3 = v * v * v;
                    v = 0.5f * v * (1.f + tanhf(0.7978845608028654f * (v + 0.044715f * x3)));
                }
                if (OUTBF)
                    ((hbf16*)Cout)[(size_t)row * N + col] = __float2bfloat16(v);
                else
                    ((float*)Cout)[(size_t)row * N + col] = v;
            }
        }
    }
}

// ---------------- MFMA flash attention ----------------
// grid (T/64, H, B), 256 threads = 4 waves; wave w owns q rows [q0+w*16, +16)
// qkv bf16 [M][3D]; y bf16 [M][D]
__global__ __launch_bounds__(256) void fattn_kernel(const hbf16* __restrict__ qkv,
                                                    hbf16* __restrict__ y) {
    int qt = gridDim.x - 1 - blockIdx.x;  // heavy tiles first
    int h = blockIdx.y, b = blockIdx.z;
    int q0 = qt * 64;
    int tid = threadIdx.x;
    int l = tid & 63, w = tid >> 6;
    int li = l & 15, lg = l >> 4;
    constexpr int RS = 3 * Dc;
    constexpr int PST = 72;  // P row stride (bf16), 144B: 16B-aligned
    constexpr int VST = 72;  // Vt row stride

    __shared__ __bf16 P_lds[4][16 * PST];
    __shared__ __bf16 Vt[64 * VST];

    // Q A-frags: lane holds Q[q0+w*16+li][ks*32+lg*8 .. +8]
    bf16x8 qf[2];
    {
        const hbf16* qp = qkv + (size_t)(b * Tc + q0 + w * 16 + li) * RS + h * HDc + lg * 8;
        qf[0] = *(const bf16x8*)qp;
        qf[1] = *(const bf16x8*)(qp + 32);
    }

    f32x4 acc_o[4] = {};
    float m_run[4], l_run[4];
#pragma unroll
    for (int r = 0; r < 4; r++) { m_run[r] = -1e30f; l_run[r] = 0.f; }

    for (int jt = 0; jt <= qt; jt++) {
        int j0 = jt * 64;
        // ---- stage V^T into LDS: Vt[d][j] ----
        {
            int j = tid >> 2;
            int dbase = (tid & 3) * 16;
            const hbf16* vp = qkv + (size_t)(b * Tc + j0 + j) * RS + 2 * Dc + h * HDc + dbase;
            bf16x8 v0 = *(const bf16x8*)vp;
            bf16x8 v1 = *(const bf16x8*)(vp + 8);
#pragma unroll
            for (int i = 0; i < 8; i++) Vt[(dbase + i) * VST + j] = v0[i];
#pragma unroll
            for (int i = 0; i < 8; i++) Vt[(dbase + 8 + i) * VST + j] = v1[i];
        }

        // ---- S = Q K^T (this wave's 16 q rows x 64 j cols) ----
        f32x4 s[4] = {};
#pragma unroll
        for (int ks = 0; ks < 2; ks++) {
#pragma unroll
            for (int n = 0; n < 4; n++) {
                const hbf16* kp = qkv + (size_t)(b * Tc + j0 + n * 16 + li) * RS + Dc + h * HDc + ks * 32 + lg * 8;
                bf16x8 kf = *(const bf16x8*)kp;
                s[n] = __builtin_amdgcn_mfma_f32_16x16x32_bf16(qf[ks], kf, s[n], 0, 0, 0);
            }
        }
#pragma unroll
        for (int n = 0; n < 4; n++)
#pragma unroll
            for (int r = 0; r < 4; r++) s[n][r] *= 0.125f;

        if (jt == qt) {  // diagonal: mask j > q (local indices share origin)
            int qloc = w * 16 + lg * 4;
#pragma unroll
            for (int n = 0; n < 4; n++) {
                int jloc = n * 16 + li;
#pragma unroll
                for (int r = 0; r < 4; r++)
                    if (jloc > qloc + r) s[n][r] = -1e30f;
            }
        }

        // ---- online softmax (rows spread over 16-lane groups) ----
        float mnew[4], scl[4];
#pragma unroll
        for (int r = 0; r < 4; r++) {
            float mx = fmaxf(fmaxf(s[0][r], s[1][r]), fmaxf(s[2][r], s[3][r]));
#pragma unroll
            for (int msk = 1; msk <= 8; msk <<= 1) mx = fmaxf(mx, __shfl_xor(mx, msk, 64));
            mnew[r] = fmaxf(m_run[r], mx);
            scl[r] = expf(m_run[r] - mnew[r]);
            m_run[r] = mnew[r];
        }
        float rs[4] = {0.f, 0.f, 0.f, 0.f};
#pragma unroll
        for (int n = 0; n < 4; n++)
#pragma unroll
            for (int r = 0; r < 4; r++) {
                float p = expf(s[n][r] - mnew[r]);
                s[n][r] = p;
                rs[r] += p;
            }
#pragma unroll
        for (int r = 0; r < 4; r++) {
#pragma unroll
            for (int msk = 1; msk <= 8; msk <<= 1) rs[r] += __shfl_xor(rs[r], msk, 64);
            l_run[r] = l_run[r] * scl[r] + rs[r];
        }

        // ---- P -> LDS (bf16), re-read as A-frags (wave-local) ----
#pragma unroll
        for (int n = 0; n < 4; n++)
#pragma unroll
            for (int r = 0; r < 4; r++) {
                hbf16 t = __float2bfloat16(s[n][r]);
                P_lds[w][(lg * 4 + r) * PST + n * 16 + li] = *(__bf16*)&t;
            }
        bf16x8 pa0 = *(const bf16x8*)&P_lds[w][li * PST + lg * 8];
        bf16x8 pa1 = *(const bf16x8*)&P_lds[w][li * PST + 32 + lg * 8];

        // ---- rescale O ----
#pragma unroll
        for (int n2 = 0; n2 < 4; n2++)
#pragma unroll
            for (int r = 0; r < 4; r++) acc_o[n2][r] *= scl[r];

        __syncthreads();  // Vt writes visible
#pragma unroll
        for (int n2 = 0; n2 < 4; n2++) {
            bf16x8 vf0 = *(const bf16x8*)&Vt[(n2 * 16 + li) * VST + lg * 8];
            bf16x8 vf1 = *(const bf16x8*)&Vt[(n2 * 16 + li) * VST + 32 + lg * 8];
            acc_o[n2] = __builtin_amdgcn_mfma_f32_16x16x32_bf16(pa0, vf0, acc_o[n2], 0, 0, 0);
            acc_o[n2] = __builtin_amdgcn_mfma_f32_16x16x32_bf16(pa1, vf1, acc_o[n2], 0, 0, 0);
        }
        __syncthreads();  // PV reads done before next stage overwrites Vt
    }

#pragma unroll
    for (int r = 0; r < 4; r++) {
        float rcp = 1.f / l_run[r];
        int row = q0 + w * 16 + lg * 4 + r;
#pragma unroll
        for (int n2 = 0; n2 < 4; n2++)
            y[(size_t)(b * Tc + row) * Dc + h * HDc + n2 * 16 + li] =
                __float2bfloat16(acc_o[n2][r] * rcp);
    }
}

extern "C" void kernel_launch(void* const* d_in, const int* in_sizes, int n_in,
                              void* d_out, int out_size, void* d_ws, size_t ws_size,
                              hipStream_t stream) {
    const int* x = (const int*)d_in[0];
    const float* wte = (const float*)d_in[1];
    const float* wpe = (const float*)d_in[2];
    const float* ln1w = (const float*)d_in[3];
    const float* ln1b = (const float*)d_in[4];
    const float* qkvw = (const float*)d_in[5];
    const float* qkvb = (const float*)d_in[6];
    const float* projw = (const float*)d_in[7];
    const float* projb = (const float*)d_in[8];
    const float* ln2w = (const float*)d_in[9];
    const float* ln2b = (const float*)d_in[10];
    const float* fcw = (const float*)d_in[11];
    const float* fcb = (const float*)d_in[12];
    const float* fcpw = (const float*)d_in[13];
    const float* fcpb = (const float*)d_in[14];
    const float* lnfw = (const float*)d_in[15];
    const float* lnfb = (const float*)d_in[16];

    char* p = (char*)d_ws;
    float* h = (float*)p;     p += (size_t)Mc * Dc * 4;      // f32 [M][D]
    hbf16* qkv = (hbf16*)p;   p += (size_t)Mc * 3 * Dc * 2;  // bf16 [M][3D]
    hbf16* a = (hbf16*)p;     p += (size_t)Mc * Dc * 2;      // bf16 [M][D]
    hbf16* y = (hbf16*)p;     p += (size_t)Mc * Dc * 2;      // bf16 [M][D]
    hbf16* mlp = (hbf16*)p;   p += (size_t)Mc * 4 * Dc * 2;  // bf16 [M][4D]
    hbf16* wq_t = (hbf16*)p;  p += (size_t)3 * Dc * Dc * 2;
    hbf16* wp_t = (hbf16*)p;  p += (size_t)Dc * Dc * 2;
    hbf16* wf_t = (hbf16*)p;  p += (size_t)4 * Dc * Dc * 2;
    hbf16* wfp_t = (hbf16*)p; p += (size_t)4 * Dc * Dc * 2;
    hbf16* wte_b = (hbf16*)p; p += (size_t)Vpad * Dc * 2;

    embed_kernel<<<(Mc * Dc + 255) / 256, 256, 0, stream>>>(x, wte, wpe, h);
    convert_wte<<<((size_t)Vpad * Dc / 4 + 255) / 256, 256, 0, stream>>>(wte, wte_b);

    dim3 tb(32, 8);
    for (int l = 0; l < Lc; l++) {
        transpose_convert<<<dim3(3 * Dc / 32, Dc / 32), tb, 0, stream>>>(
            qkvw + (size_t)l * Dc * 3 * Dc, wq_t, Dc, 3 * Dc);
        transpose_convert<<<dim3(Dc / 32, Dc / 32), tb, 0, stream>>>(
            projw + (size_t)l * Dc * Dc, wp_t, Dc, Dc);
        transpose_convert<<<dim3(4 * Dc / 32, Dc / 32), tb, 0, stream>>>(
            fcw + (size_t)l * Dc * 4 * Dc, wf_t, Dc, 4 * Dc);
        transpose_convert<<<dim3(Dc / 32, 4 * Dc / 32), tb, 0, stream>>>(
            fcpw + (size_t)l * 4 * Dc * Dc, wfp_t, 4 * Dc, Dc);

        ln_kernel<<<Mc, 256, 0, stream>>>(h, ln1w + (size_t)l * Dc, ln1b + (size_t)l * Dc, a);
        mm_kernel<0, true><<<dim3(3 * Dc / 128, Mc / 128), 256, 0, stream>>>(
            a, wq_t, qkvb + (size_t)l * 3 * Dc, nullptr, qkv, Mc, 3 * Dc, Dc);
        fattn_kernel<<<dim3(Tc / 64, Hc, Bc), 256, 0, stream>>>(qkv, y);
        mm_kernel<1, false><<<dim3(Dc / 128, Mc / 128), 256, 0, stream>>>(
            y, wp_t, projb + (size_t)l * Dc, h, h, Mc, Dc, Dc);
        ln_kernel<<<Mc, 256, 0, stream>>>(h, ln2w + (size_t)l * Dc, ln2b + (size_t)l * Dc, a);
        mm_kernel<2, true><<<dim3(4 * Dc / 128, Mc / 128), 256, 0, stream>>>(
            a, wf_t, fcb + (size_t)l * 4 * Dc, nullptr, mlp, Mc, 4 * Dc, Dc);
        mm_kernel<1, false><<<dim3(Dc / 128, Mc / 128), 256, 0, stream>>>(
            mlp, wfp_t, fcpb + (size_t)l * Dc, h, h, Mc, Dc, 4 * Dc);
    }

    ln_kernel<<<Mc, 256, 0, stream>>>(h, lnfw, lnfb, a);
    mm_kernel<0, false><<<dim3(Vpad / 128, Mc / 128), 256, 0, stream>>>(
        a, wte_b, nullptr, nullptr, (float*)d_out, Mc, Vc, Dc);
}

// Round 5
// 3082.890 us; speedup vs baseline: 8.4897x; 1.0064x over previous
//
#include <hip/hip_runtime.h>
#include <hip/hip_bf16.h>

typedef __hip_bfloat16 hbf16;
using bf16x8 = __attribute__((ext_vector_type(8))) __bf16;
using f32x4 = __attribute__((ext_vector_type(4))) float;

// GPT-2 small: L=12 H=12 D=768 V=50257 T=1024 B=2, HD=64
constexpr int Lc = 12, Hc = 12, Dc = 768, Vc = 50257, Tc = 1024, Bc = 2, HDc = 64;
constexpr int Mc = Bc * Tc;  // 2048 rows
constexpr int Vpad = 50304;  // 393*128, zero-padded vocab

#define GLD16(gp, lp)                                               \
    __builtin_amdgcn_global_load_lds(                               \
        (__attribute__((address_space(1))) void*)(void*)(gp),       \
        (__attribute__((address_space(3))) void*)(void*)(lp), 16, 0, 0)

// ---------------- embedding: h = wte[x] + wpe[t] (f32) ----------------
__global__ void embed_kernel(const int* __restrict__ x, const float* __restrict__ wte,
                             const float* __restrict__ wpe, float* __restrict__ h) {
    int i = blockIdx.x * blockDim.x + threadIdx.x;
    if (i >= Mc * Dc) return;
    int m = i / Dc, d = i - m * Dc;
    int t = m % Tc;
    int tok = x[m];
    h[i] = wte[(size_t)tok * Dc + d] + wpe[(size_t)t * Dc + d];
}

// ---------------- layernorm: one wave per row, shuffle reduce, f32 in -> bf16 out --
__global__ __launch_bounds__(256) void ln_kernel(const float* __restrict__ x,
                                                 const float* __restrict__ w,
                                                 const float* __restrict__ b,
                                                 hbf16* __restrict__ out) {
    int wv = threadIdx.x >> 6, lane = threadIdx.x & 63;
    int row = blockIdx.x * 4 + wv;
    const float4* xr = (const float4*)(x + (size_t)row * Dc);
    float4 v[3];
    float s = 0.f, sq = 0.f;
#pragma unroll
    for (int i = 0; i < 3; i++) {
        v[i] = xr[i * 64 + lane];
        s += v[i].x + v[i].y + v[i].z + v[i].w;
        sq += v[i].x * v[i].x + v[i].y * v[i].y + v[i].z * v[i].z + v[i].w * v[i].w;
    }
#pragma unroll
    for (int o = 32; o > 0; o >>= 1) {
        s += __shfl_xor(s, o, 64);
        sq += __shfl_xor(sq, o, 64);
    }
    float mean = s * (1.f / Dc);
    float var = sq * (1.f / Dc) - mean * mean;
    float rstd = rsqrtf(var + 1e-5f);
#pragma unroll
    for (int i = 0; i < 3; i++) {
        int c = (i * 64 + lane) * 4;
        float4 wv4 = *(const float4*)(w + c);
        float4 bv4 = *(const float4*)(b + c);
        float r0 = (v[i].x - mean) * rstd * wv4.x + bv4.x;
        float r1 = (v[i].y - mean) * rstd * wv4.y + bv4.y;
        float r2 = (v[i].z - mean) * rstd * wv4.z + bv4.z;
        float r3 = (v[i].w - mean) * rstd * wv4.w + bv4.w;
        __bf16 q0 = (__bf16)r0, q1 = (__bf16)r1, q2 = (__bf16)r2, q3 = (__bf16)r3;
        ushort4 u;
        u.x = *(unsigned short*)&q0; u.y = *(unsigned short*)&q1;
        u.z = *(unsigned short*)&q2; u.w = *(unsigned short*)&q3;
        *(ushort4*)(out + (size_t)row * Dc + c) = u;
    }
}

// ---------------- fused per-layer weight transpose: 4 matrices in one launch -------
__global__ __launch_bounds__(256) void transpose4_kernel(
    const float* __restrict__ s0, const float* __restrict__ s1,
    const float* __restrict__ s2, const float* __restrict__ s3,
    hbf16* __restrict__ d0, hbf16* __restrict__ d1,
    hbf16* __restrict__ d2, hbf16* __restrict__ d3) {
    int z = blockIdx.z;
    const int Ks[4] = {768, 768, 768, 3072};
    const int Ns[4] = {2304, 768, 3072, 768};
    int K = Ks[z], N = Ns[z];
    if ((int)blockIdx.x >= N / 32 || (int)blockIdx.y >= K / 32) return;
    const float* W = z == 0 ? s0 : z == 1 ? s1 : z == 2 ? s2 : s3;
    hbf16* Wt = z == 0 ? d0 : z == 1 ? d1 : z == 2 ? d2 : d3;

    __shared__ float tile[32][33];
    int n0 = blockIdx.x * 32, k0 = blockIdx.y * 32;
    int tx = threadIdx.x & 31, ty = threadIdx.x >> 5;  // 32x8
#pragma unroll
    for (int i = 0; i < 4; i++) {
        int r = ty + i * 8;
        tile[r][tx] = W[(size_t)(k0 + r) * N + n0 + tx];
    }
    __syncthreads();
#pragma unroll
    for (int i = 0; i < 4; i++) {
        int r = ty + i * 8;
        Wt[(size_t)(n0 + r) * K + k0 + tx] = __float2bfloat16(tile[tx][r]);
    }
}

// ---------------- wte f32 [V][D] -> bf16 [Vpad][D] (zero pad) ----------------
__global__ void convert_wte(const float* __restrict__ wte, hbf16* __restrict__ out) {
    size_t i4 = ((size_t)blockIdx.x * 256 + threadIdx.x) * 4;
    if (i4 >= (size_t)Vpad * Dc) return;
    if (i4 < (size_t)Vc * Dc) {
#pragma unroll
        for (int j = 0; j < 4; j++) out[i4 + j] = __float2bfloat16(wte[i4 + j]);
    } else {
#pragma unroll
        for (int j = 0; j < 4; j++) out[i4 + j] = __float2bfloat16(0.f);
    }
}

// ---------------- MFMA GEMM 128x128 (per-layer): C = A @ Bt^T + epilogue ----------
// EPI: 0 = +bias, 1 = +bias +f32 residual, 2 = +bias + tanh-GELU
template <int EPI, bool OUTBF>
__global__ __launch_bounds__(256) void mm_kernel(const hbf16* __restrict__ A,
                                                 const hbf16* __restrict__ Bt,
                                                 const float* __restrict__ bias,
                                                 const float* __restrict__ resid,
                                                 void* __restrict__ Cout,
                                                 int M, int N, int K) {
    __shared__ __bf16 As[128 * 32];
    __shared__ __bf16 Bs[128 * 32];
    int tid = threadIdx.x;
    int l = tid & 63, w = tid >> 6;
    int wr = w >> 1, wc = w & 1;
    int m0 = blockIdx.y * 128, n0 = blockIdx.x * 128;

    int off0 = w * 2048 + l * 16;  // byte offset in 8KB tile
    int r0 = off0 >> 6, c0 = (off0 & 63) >> 1;
    int off1 = off0 + 1024;
    int r1 = off1 >> 6, c1 = (off1 & 63) >> 1;

    const hbf16* pA0 = A + (size_t)(m0 + r0) * K + c0;
    const hbf16* pA1 = A + (size_t)(m0 + r1) * K + c1;
    const hbf16* pB0 = Bt + (size_t)(n0 + r0) * K + c0;
    const hbf16* pB1 = Bt + (size_t)(n0 + r1) * K + c1;
    __bf16* lA0 = As + w * 1024;
    __bf16* lA1 = As + w * 1024 + 512;
    __bf16* lB0 = Bs + w * 1024;
    __bf16* lB1 = Bs + w * 1024 + 512;

    int lr = l & 15, lg = l >> 4;
    int aoff[4], boff[4];
#pragma unroll
    for (int m = 0; m < 4; m++) aoff[m] = (wr * 64 + m * 16 + lr) * 32 + lg * 8;
#pragma unroll
    for (int n = 0; n < 4; n++) boff[n] = (wc * 64 + n * 16 + lr) * 32 + lg * 8;

    f32x4 acc[4][4] = {};

    for (int k0 = 0; k0 < K; k0 += 32) {
        GLD16(pA0, lA0);
        GLD16(pA1, lA1);
        GLD16(pB0, lB0);
        GLD16(pB1, lB1);
        pA0 += 32; pA1 += 32; pB0 += 32; pB1 += 32;
        __syncthreads();
        bf16x8 af[4], bfr[4];
#pragma unroll
        for (int m = 0; m < 4; m++) af[m] = *(const bf16x8*)&As[aoff[m]];
#pragma unroll
        for (int n = 0; n < 4; n++) bfr[n] = *(const bf16x8*)&Bs[boff[n]];
#pragma unroll
        for (int m = 0; m < 4; m++)
#pragma unroll
            for (int n = 0; n < 4; n++)
                acc[m][n] = __builtin_amdgcn_mfma_f32_16x16x32_bf16(af[m], bfr[n], acc[m][n], 0, 0, 0);
        __syncthreads();
    }

#pragma unroll
    for (int n = 0; n < 4; n++) {
        int col = n0 + wc * 64 + n * 16 + lr;
        bool cok = col < N;
        float bv = (bias && cok) ? bias[col] : 0.f;
#pragma unroll
        for (int m = 0; m < 4; m++) {
#pragma unroll
            for (int r = 0; r < 4; r++) {
                int row = m0 + wr * 64 + m * 16 + lg * 4 + r;
                if (!cok) continue;
                float v = acc[m][n][r] + bv;
                if (EPI == 1) v += resid[(size_t)row * N + col];
                if (EPI == 2) {
                    float x3 = v * v * v;
                    v = 0.5f * v * (1.f + tanhf(0.7978845608028654f * (v + 0.044715f * x3)));
                }
                if (OUTBF)
                    ((hbf16*)Cout)[(size_t)row * N + col] = __float2bfloat16(v);
                else
                    ((float*)Cout)[(size_t)row * N + col] = v;
            }
        }
    }
}

// ---------------- MFMA GEMM 256x128, 512 threads, XCD-swizzled (lm_head) ----------
// 8 waves: wr = w>>1 in [0,4) rows, wc = w&1 cols. f32 out, optional bias.
__global__ __launch_bounds__(512) void mm2_kernel(const hbf16* __restrict__ A,
                                                  const hbf16* __restrict__ Bt,
                                                  float* __restrict__ Cout,
                                                  int M, int N, int K) {
    __shared__ __bf16 As[256 * 32];  // 16 KB
    __shared__ __bf16 Bs[128 * 32];  // 8 KB
    int tid = threadIdx.x;
    int l = tid & 63, w = tid >> 6;
    int wr = w >> 1, wc = w & 1;

    // XCD swizzle: consecutive-linear blocks share an N-panel; chunk per XCD.
    int gy = gridDim.y;
    int nwg = gridDim.x * gy;
    int lin = blockIdx.x * gy + blockIdx.y;
    int q = nwg >> 3;
    int neu = (lin & 7) * q + (lin >> 3);
    int m0 = (neu % gy) * 256, n0 = (neu / gy) * 128;

    // A staging: wave w -> issues 2w, 2w+1; issue j covers rows j*16..+15 (64B/row)
    int rA0 = 2 * w * 16 + (l >> 2), cA = (l & 3) * 8;
    int rA1 = rA0 + 16;
    const hbf16* pA0 = A + (size_t)(m0 + rA0) * K + cA;
    const hbf16* pA1 = A + (size_t)(m0 + rA1) * K + cA;
    // B staging: wave w -> issue w; rows w*16..+15
    int rB = w * 16 + (l >> 2);
    const hbf16* pB = Bt + (size_t)(n0 + rB) * K + cA;
    __bf16* lA0 = As + 2 * w * 512;
    __bf16* lA1 = As + 2 * w * 512 + 512;
    __bf16* lB = Bs + w * 512;

    int lr = l & 15, lg = l >> 4;
    int aoff[4], boff[4];
#pragma unroll
    for (int m = 0; m < 4; m++) aoff[m] = (wr * 64 + m * 16 + lr) * 32 + lg * 8;
#pragma unroll
    for (int n = 0; n < 4; n++) boff[n] = (wc * 64 + n * 16 + lr) * 32 + lg * 8;

    f32x4 acc[4][4] = {};

    for (int k0 = 0; k0 < K; k0 += 32) {
        GLD16(pA0, lA0);
        GLD16(pA1, lA1);
        GLD16(pB, lB);
        pA0 += 32; pA1 += 32; pB += 32;
        __syncthreads();
        bf16x8 af[4], bfr[4];
#pragma unroll
        for (int m = 0; m < 4; m++) af[m] = *(const bf16x8*)&As[aoff[m]];
#pragma unroll
        for (int n = 0; n < 4; n++) bfr[n] = *(const bf16x8*)&Bs[boff[n]];
#pragma unroll
        for (int m = 0; m < 4; m++)
#pragma unroll
            for (int n = 0; n < 4; n++)
                acc[m][n] = __builtin_amdgcn_mfma_f32_16x16x32_bf16(af[m], bfr[n], acc[m][n], 0, 0, 0);
        __syncthreads();
    }

#pragma unroll
    for (int n = 0; n < 4; n++) {
        int col = n0 + wc * 64 + n * 16 + lr;
        if (col >= N) continue;
#pragma unroll
        for (int m = 0; m < 4; m++) {
#pragma unroll
            for (int r = 0; r < 4; r++) {
                int row = m0 + wr * 64 + m * 16 + lg * 4 + r;
                Cout[(size_t)row * N + col] = acc[m][n][r];
            }
        }
    }
}

// ---------------- MFMA flash attention ----------------
__global__ __launch_bounds__(256) void fattn_kernel(const hbf16* __restrict__ qkv,
                                                    hbf16* __restrict__ y) {
    int qt = gridDim.x - 1 - blockIdx.x;  // heavy tiles first
    int h = blockIdx.y, b = blockIdx.z;
    int q0 = qt * 64;
    int tid = threadIdx.x;
    int l = tid & 63, w = tid >> 6;
    int li = l & 15, lg = l >> 4;
    constexpr int RS = 3 * Dc;
    constexpr int PST = 72;
    constexpr int VST = 72;

    __shared__ __bf16 P_lds[4][16 * PST];
    __shared__ __bf16 Vt[64 * VST];

    bf16x8 qf[2];
    {
        const hbf16* qp = qkv + (size_t)(b * Tc + q0 + w * 16 + li) * RS + h * HDc + lg * 8;
        qf[0] = *(const bf16x8*)qp;
        qf[1] = *(const bf16x8*)(qp + 32);
    }

    f32x4 acc_o[4] = {};
    float m_run[4], l_run[4];
#pragma unroll
    for (int r = 0; r < 4; r++) { m_run[r] = -1e30f; l_run[r] = 0.f; }

    for (int jt = 0; jt <= qt; jt++) {
        int j0 = jt * 64;
        {
            int j = tid >> 2;
            int dbase = (tid & 3) * 16;
            const hbf16* vp = qkv + (size_t)(b * Tc + j0 + j) * RS + 2 * Dc + h * HDc + dbase;
            bf16x8 v0 = *(const bf16x8*)vp;
            bf16x8 v1 = *(const bf16x8*)(vp + 8);
#pragma unroll
            for (int i = 0; i < 8; i++) Vt[(dbase + i) * VST + j] = v0[i];
#pragma unroll
            for (int i = 0; i < 8; i++) Vt[(dbase + 8 + i) * VST + j] = v1[i];
        }

        f32x4 s[4] = {};
#pragma unroll
        for (int ks = 0; ks < 2; ks++) {
#pragma unroll
            for (int n = 0; n < 4; n++) {
                const hbf16* kp = qkv + (size_t)(b * Tc + j0 + n * 16 + li) * RS + Dc + h * HDc + ks * 32 + lg * 8;
                bf16x8 kf = *(const bf16x8*)kp;
                s[n] = __builtin_amdgcn_mfma_f32_16x16x32_bf16(qf[ks], kf, s[n], 0, 0, 0);
            }
        }
#pragma unroll
        for (int n = 0; n < 4; n++)
#pragma unroll
            for (int r = 0; r < 4; r++) s[n][r] *= 0.125f;

        if (jt == qt) {
            int qloc = w * 16 + lg * 4;
#pragma unroll
            for (int n = 0; n < 4; n++) {
                int jloc = n * 16 + li;
#pragma unroll
                for (int r = 0; r < 4; r++)
                    if (jloc > qloc + r) s[n][r] = -1e30f;
            }
        }

        float mnew[4], scl[4];
#pragma unroll
        for (int r = 0; r < 4; r++) {
            float mx = fmaxf(fmaxf(s[0][r], s[1][r]), fmaxf(s[2][r], s[3][r]));
#pragma unroll
            for (int msk = 1; msk <= 8; msk <<= 1) mx = fmaxf(mx, __shfl_xor(mx, msk, 64));
            mnew[r] = fmaxf(m_run[r], mx);
            scl[r] = expf(m_run[r] - mnew[r]);
            m_run[r] = mnew[r];
        }
        float rs[4] = {0.f, 0.f, 0.f, 0.f};
#pragma unroll
        for (int n = 0; n < 4; n++)
#pragma unroll
            for (int r = 0; r < 4; r++) {
                float p = expf(s[n][r] - mnew[r]);
                s[n][r] = p;
                rs[r] += p;
            }
#pragma unroll
        for (int r = 0; r < 4; r++) {
#pragma unroll
            for (int msk = 1; msk <= 8; msk <<= 1) rs[r] += __shfl_xor(rs[r], msk, 64);
            l_run[r] = l_run[r] * scl[r] + rs[r];
        }

#pragma unroll
        for (int n = 0; n < 4; n++)
#pragma unroll
            for (int r = 0; r < 4; r++) {
                hbf16 t = __float2bfloat16(s[n][r]);
                P_lds[w][(lg * 4 + r) * PST + n * 16 + li] = *(__bf16*)&t;
            }
        bf16x8 pa0 = *(const bf16x8*)&P_lds[w][li * PST + lg * 8];
        bf16x8 pa1 = *(const bf16x8*)&P_lds[w][li * PST + 32 + lg * 8];

#pragma unroll
        for (int n2 = 0; n2 < 4; n2++)
#pragma unroll
            for (int r = 0; r < 4; r++) acc_o[n2][r] *= scl[r];

        __syncthreads();
#pragma unroll
        for (int n2 = 0; n2 < 4; n2++) {
            bf16x8 vf0 = *(const bf16x8*)&Vt[(n2 * 16 + li) * VST + lg * 8];
            bf16x8 vf1 = *(const bf16x8*)&Vt[(n2 * 16 + li) * VST + 32 + lg * 8];
            acc_o[n2] = __builtin_amdgcn_mfma_f32_16x16x32_bf16(pa0, vf0, acc_o[n2], 0, 0, 0);
            acc_o[n2] = __builtin_amdgcn_mfma_f32_16x16x32_bf16(pa1, vf1, acc_o[n2], 0, 0, 0);
        }
        __syncthreads();
    }

#pragma unroll
    for (int r = 0; r < 4; r++) {
        float rcp = 1.f / l_run[r];
        int row = q0 + w * 16 + lg * 4 + r;
#pragma unroll
        for (int n2 = 0; n2 < 4; n2++)
            y[(size_t)(b * Tc + row) * Dc + h * HDc + n2 * 16 + li] =
                __float2bfloat16(acc_o[n2][r] * rcp);
    }
}

extern "C" void kernel_launch(void* const* d_in, const int* in_sizes, int n_in,
                              void* d_out, int out_size, void* d_ws, size_t ws_size,
                              hipStream_t stream) {
    const int* x = (const int*)d_in[0];
    const float* wte = (const float*)d_in[1];
    const float* wpe = (const float*)d_in[2];
    const float* ln1w = (const float*)d_in[3];
    const float* ln1b = (const float*)d_in[4];
    const float* qkvw = (const float*)d_in[5];
    const float* qkvb = (const float*)d_in[6];
    const float* projw = (const float*)d_in[7];
    const float* projb = (const float*)d_in[8];
    const float* ln2w = (const float*)d_in[9];
    const float* ln2b = (const float*)d_in[10];
    const float* fcw = (const float*)d_in[11];
    const float* fcb = (const float*)d_in[12];
    const float* fcpw = (const float*)d_in[13];
    const float* fcpb = (const float*)d_in[14];
    const float* lnfw = (const float*)d_in[15];
    const float* lnfb = (const float*)d_in[16];

    char* p = (char*)d_ws;
    float* h = (float*)p;     p += (size_t)Mc * Dc * 4;      // f32 [M][D]
    hbf16* qkv = (hbf16*)p;   p += (size_t)Mc * 3 * Dc * 2;  // bf16 [M][3D]
    hbf16* a = (hbf16*)p;     p += (size_t)Mc * Dc * 2;      // bf16 [M][D]
    hbf16* y = (hbf16*)p;     p += (size_t)Mc * Dc * 2;      // bf16 [M][D]
    hbf16* mlp = (hbf16*)p;   p += (size_t)Mc * 4 * Dc * 2;  // bf16 [M][4D]
    hbf16* wq_t = (hbf16*)p;  p += (size_t)3 * Dc * Dc * 2;
    hbf16* wp_t = (hbf16*)p;  p += (size_t)Dc * Dc * 2;
    hbf16* wf_t = (hbf16*)p;  p += (size_t)4 * Dc * Dc * 2;
    hbf16* wfp_t = (hbf16*)p; p += (size_t)4 * Dc * Dc * 2;
    hbf16* wte_b = (hbf16*)p; p += (size_t)Vpad * Dc * 2;

    embed_kernel<<<(Mc * Dc + 255) / 256, 256, 0, stream>>>(x, wte, wpe, h);
    convert_wte<<<((size_t)Vpad * Dc / 4 + 255) / 256, 256, 0, stream>>>(wte, wte_b);

    for (int l = 0; l < Lc; l++) {
        transpose4_kernel<<<dim3(96, 96, 4), 256, 0, stream>>>(
            qkvw + (size_t)l * Dc * 3 * Dc, projw + (size_t)l * Dc * Dc,
            fcw + (size_t)l * Dc * 4 * Dc, fcpw + (size_t)l * 4 * Dc * Dc,
            wq_t, wp_t, wf_t, wfp_t);

        ln_kernel<<<Mc / 4, 256, 0, stream>>>(h, ln1w + (size_t)l * Dc, ln1b + (size_t)l * Dc, a);
        mm_kernel<0, true><<<dim3(3 * Dc / 128, Mc / 128), 256, 0, stream>>>(
            a, wq_t, qkvb + (size_t)l * 3 * Dc, nullptr, qkv, Mc, 3 * Dc, Dc);
        fattn_kernel<<<dim3(Tc / 64, Hc, Bc), 256, 0, stream>>>(qkv, y);
        mm_kernel<1, false><<<dim3(Dc / 128, Mc / 128), 256, 0, stream>>>(
            y, wp_t, projb + (size_t)l * Dc, h, h, Mc, Dc, Dc);
        ln_kernel<<<Mc / 4, 256, 0, stream>>>(h, ln2w + (size_t)l * Dc, ln2b + (size_t)l * Dc, a);
        mm_kernel<2, true><<<dim3(4 * Dc / 128, Mc / 128), 256, 0, stream>>>(
            a, wf_t, fcb + (size_t)l * 4 * Dc, nullptr, mlp, Mc, 4 * Dc, Dc);
        mm_kernel<1, false><<<dim3(Dc / 128, Mc / 128), 256, 0, stream>>>(
            mlp, wfp_t, fcpb + (size_t)l * Dc, h, h, Mc, Dc, 4 * Dc);
    }

    ln_kernel<<<Mc / 4, 256, 0, stream>>>(h, lnfw, lnfb, a);
    mm2_kernel<<<dim3(Vpad / 128, Mc / 256), 512, 0, stream>>>(
        a, wte_b, (float*)d_out, Mc, Vc, Dc);
}

// Round 7
// 2682.898 us; speedup vs baseline: 9.7555x; 1.1491x over previous
//
#include <hip/hip_runtime.h>
#include <hip/hip_bf16.h>

typedef __hip_bfloat16 hbf16;
using bf16x8 = __attribute__((ext_vector_type(8))) __bf16;
using f32x4 = __attribute__((ext_vector_type(4))) float;

// GPT-2 small: L=12 H=12 D=768 V=50257 T=1024 B=2, HD=64
constexpr int Lc = 12, Hc = 12, Dc = 768, Vc = 50257, Tc = 1024, Bc = 2, HDc = 64;
constexpr int Mc = Bc * Tc;  // 2048 rows
constexpr int Vpad = 50304;  // 393*128, zero-padded vocab

#define GLD16(gp, lp)                                               \
    __builtin_amdgcn_global_load_lds(                               \
        (__attribute__((address_space(1))) void*)(void*)(gp),       \
        (__attribute__((address_space(3))) void*)(void*)(lp), 16, 0, 0)

// ---------------- embedding: h = wte[x] + wpe[t] (f32) ----------------
__global__ void embed_kernel(const int* __restrict__ x, const float* __restrict__ wte,
                             const float* __restrict__ wpe, float* __restrict__ h) {
    int i = blockIdx.x * blockDim.x + threadIdx.x;
    if (i >= Mc * Dc) return;
    int m = i / Dc, d = i - m * Dc;
    int t = m % Tc;
    int tok = x[m];
    h[i] = wte[(size_t)tok * Dc + d] + wpe[(size_t)t * Dc + d];
}

// ---------------- layernorm: one wave per row, shuffle reduce, f32 in -> bf16 out --
__global__ __launch_bounds__(256) void ln_kernel(const float* __restrict__ x,
                                                 const float* __restrict__ w,
                                                 const float* __restrict__ b,
                                                 hbf16* __restrict__ out) {
    int wv = threadIdx.x >> 6, lane = threadIdx.x & 63;
    int row = blockIdx.x * 4 + wv;
    const float4* xr = (const float4*)(x + (size_t)row * Dc);
    float4 v[3];
    float s = 0.f, sq = 0.f;
#pragma unroll
    for (int i = 0; i < 3; i++) {
        v[i] = xr[i * 64 + lane];
        s += v[i].x + v[i].y + v[i].z + v[i].w;
        sq += v[i].x * v[i].x + v[i].y * v[i].y + v[i].z * v[i].z + v[i].w * v[i].w;
    }
#pragma unroll
    for (int o = 32; o > 0; o >>= 1) {
        s += __shfl_xor(s, o, 64);
        sq += __shfl_xor(sq, o, 64);
    }
    float mean = s * (1.f / Dc);
    float var = sq * (1.f / Dc) - mean * mean;
    float rstd = rsqrtf(var + 1e-5f);
#pragma unroll
    for (int i = 0; i < 3; i++) {
        int c = (i * 64 + lane) * 4;
        float4 wv4 = *(const float4*)(w + c);
        float4 bv4 = *(const float4*)(b + c);
        float r0 = (v[i].x - mean) * rstd * wv4.x + bv4.x;
        float r1 = (v[i].y - mean) * rstd * wv4.y + bv4.y;
        float r2 = (v[i].z - mean) * rstd * wv4.z + bv4.z;
        float r3 = (v[i].w - mean) * rstd * wv4.w + bv4.w;
        __bf16 q0 = (__bf16)r0, q1 = (__bf16)r1, q2 = (__bf16)r2, q3 = (__bf16)r3;
        ushort4 u;
        u.x = *(unsigned short*)&q0; u.y = *(unsigned short*)&q1;
        u.z = *(unsigned short*)&q2; u.w = *(unsigned short*)&q3;
        *(ushort4*)(out + (size_t)row * Dc + c) = u;
    }
}

// ---------------- fused per-layer weight transpose, exact 1D grid (6912 blocks) ----
__global__ __launch_bounds__(256) void transpose4_kernel(
    const float* __restrict__ s0, const float* __restrict__ s1,
    const float* __restrict__ s2, const float* __restrict__ s3,
    hbf16* __restrict__ d0, hbf16* __restrict__ d1,
    hbf16* __restrict__ d2, hbf16* __restrict__ d3) {
    int id = blockIdx.x;
    int bx, by, K, N;
    const float* W;
    hbf16* Wt;
    if (id < 1728)      { int t = id;        bx = t % 72; by = t / 72; K = 768;  N = 2304; W = s0; Wt = d0; }
    else if (id < 2304) { int t = id - 1728; bx = t % 24; by = t / 24; K = 768;  N = 768;  W = s1; Wt = d1; }
    else if (id < 4608) { int t = id - 2304; bx = t % 96; by = t / 96; K = 768;  N = 3072; W = s2; Wt = d2; }
    else                { int t = id - 4608; bx = t % 24; by = t / 24; K = 3072; N = 768;  W = s3; Wt = d3; }

    __shared__ float tile[32][33];
    int n0 = bx * 32, k0 = by * 32;
    int tx = threadIdx.x & 31, ty = threadIdx.x >> 5;  // 32x8
#pragma unroll
    for (int i = 0; i < 4; i++) {
        int r = ty + i * 8;
        tile[r][tx] = W[(size_t)(k0 + r) * N + n0 + tx];
    }
    __syncthreads();
#pragma unroll
    for (int i = 0; i < 4; i++) {
        int r = ty + i * 8;
        Wt[(size_t)(n0 + r) * K + k0 + tx] = __float2bfloat16(tile[tx][r]);
    }
}

// ---------------- wte f32 [V][D] -> bf16 [Vpad][D] (zero pad) ----------------
__global__ void convert_wte(const float* __restrict__ wte, hbf16* __restrict__ out) {
    size_t i4 = ((size_t)blockIdx.x * 256 + threadIdx.x) * 4;
    if (i4 >= (size_t)Vpad * Dc) return;
    if (i4 < (size_t)Vc * Dc) {
#pragma unroll
        for (int j = 0; j < 4; j++) out[i4 + j] = __float2bfloat16(wte[i4 + j]);
    } else {
#pragma unroll
        for (int j = 0; j < 4; j++) out[i4 + j] = __float2bfloat16(0.f);
    }
}

// ---------------- MFMA GEMM 128xBN: C = A @ Bt^T + epilogue ----------
// EPI: 0 = +bias, 1 = +bias +f32 residual, 2 = +bias + tanh-GELU
// XOR bank-swizzle (slot ^= row&3) on staged source + frag reads (rule #21).
// XCD-chunked block swizzle on hw dispatch order (x fastest), m-fastest decode.
template <int EPI, bool OUTBF, int BN>
__global__ __launch_bounds__(256) void mm_kernel(const hbf16* __restrict__ A,
                                                 const hbf16* __restrict__ Bt,
                                                 const float* __restrict__ bias,
                                                 const float* __restrict__ resid,
                                                 void* __restrict__ Cout,
                                                 int M, int N, int K) {
    constexpr int NF = BN / 32;  // n-frags per wave
    __shared__ __bf16 As[128 * 32];
    __shared__ __bf16 Bs[BN * 32];
    int tid = threadIdx.x;
    int l = tid & 63, w = tid >> 6;
    int wr = w >> 1, wc = w & 1;

    // XCD swizzle: hwlin%8 = XCD; contiguous work chunk per XCD, m fastest.
    int gx = gridDim.x, gy = gridDim.y;
    int nwg = gx * gy;                       // divisible by 8 for all our launches
    int hwlin = blockIdx.y * gx + blockIdx.x;
    int wk = (hwlin & 7) * (nwg >> 3) + (hwlin >> 3);
    int m0 = (wk % gy) * 128;
    int n0 = (wk / gy) * BN;

    // staging: slot swizzle s' = s ^ (row&3); 256 threads -> 64 rows / issue
    int sr = tid >> 2, sc = tid & 3;
    int scs = (sc ^ (sr & 3)) * 8;
    const hbf16* pA0 = A + (size_t)(m0 + sr) * K + scs;
    const hbf16* pA1 = A + (size_t)(m0 + 64 + sr) * K + scs;
    const hbf16* pB0 = Bt + (size_t)(n0 + sr) * K + scs;
    const hbf16* pB1 = pB0;
    if constexpr (BN == 128) pB1 = Bt + (size_t)(n0 + 64 + sr) * K + scs;
    __bf16* lA0 = As + tid * 8;
    __bf16* lA1 = As + 2048 + tid * 8;
    __bf16* lB0 = Bs + tid * 8;
    __bf16* lB1 = Bs + 2048 + tid * 8;

    int lr = l & 15, lg = l >> 4;
    int ksl = (lg ^ (lr & 3)) * 8;  // swizzled k-slot for frag reads
    int aoff[4], boff[NF];
#pragma unroll
    for (int m = 0; m < 4; m++) aoff[m] = (wr * 64 + m * 16 + lr) * 32 + ksl;
#pragma unroll
    for (int n = 0; n < NF; n++) boff[n] = (wc * (BN / 2) + n * 16 + lr) * 32 + ksl;

    f32x4 acc[4][NF] = {};

    for (int k0 = 0; k0 < K; k0 += 32) {
        GLD16(pA0, lA0);
        GLD16(pA1, lA1);
        GLD16(pB0, lB0);
        if constexpr (BN == 128) GLD16(pB1, lB1);
        pA0 += 32; pA1 += 32; pB0 += 32;
        if constexpr (BN == 128) pB1 += 32;
        __syncthreads();
        bf16x8 af[4], bfr[NF];
#pragma unroll
        for (int m = 0; m < 4; m++) af[m] = *(const bf16x8*)&As[aoff[m]];
#pragma unroll
        for (int n = 0; n < NF; n++) bfr[n] = *(const bf16x8*)&Bs[boff[n]];
#pragma unroll
        for (int m = 0; m < 4; m++)
#pragma unroll
            for (int n = 0; n < NF; n++)
                acc[m][n] = __builtin_amdgcn_mfma_f32_16x16x32_bf16(af[m], bfr[n], acc[m][n], 0, 0, 0);
        __syncthreads();
    }

#pragma unroll
    for (int n = 0; n < NF; n++) {
        int col = n0 + wc * (BN / 2) + n * 16 + lr;
        bool cok = col < N;
        float bv = (bias && cok) ? bias[col] : 0.f;
#pragma unroll
        for (int m = 0; m < 4; m++) {
#pragma unroll
            for (int r = 0; r < 4; r++) {
                int row = m0 + wr * 64 + m * 16 + lg * 4 + r;
                if (!cok) continue;
                float v = acc[m][n][r] + bv;
                if (EPI == 1) v += resid[(size_t)row * N + col];
                if (EPI == 2) {
                    float x3 = v * v * v;
                    v = 0.5f * v * (1.f + tanhf(0.7978845608028654f * (v + 0.044715f * x3)));
                }
                if (OUTBF)
                    ((hbf16*)Cout)[(size_t)row * N + col] = __float2bfloat16(v);
                else
                    ((float*)Cout)[(size_t)row * N + col] = v;
            }
        }
    }
}

// ---------------- MFMA GEMM 256x128, 512 threads (lm_head, f32 out) ----------
// 512 threads: each GLD16 issue covers 128 rows (8 KB). A = 2 issues, B = 1.
__global__ __launch_bounds__(512) void mm2_kernel(const hbf16* __restrict__ A,
                                                  const hbf16* __restrict__ Bt,
                                                  float* __restrict__ Cout,
                                                  int M, int N, int K) {
    __shared__ __bf16 As[256 * 32];  // 16 KB
    __shared__ __bf16 Bs[128 * 32];  // 8 KB
    int tid = threadIdx.x;
    int l = tid & 63, w = tid >> 6;
    int wr = w >> 1, wc = w & 1;

    // XCD swizzle on hw dispatch order; m fastest within chunk (B-panel reuse in L2)
    int gx = gridDim.x, gy = gridDim.y;  // gy = M/256 = 8
    int nwg = gx * gy;                   // 3144, /8 = 393
    int hwlin = blockIdx.y * gx + blockIdx.x;
    int wk = (hwlin & 7) * (nwg >> 3) + (hwlin >> 3);
    int m0 = (wk & 7) * 256;
    int n0 = (wk >> 3) * 128;

    // staging: sr in [0,128) with 512 threads
    int sr = tid >> 2, sc = tid & 3;
    int scs = (sc ^ (sr & 3)) * 8;
    const hbf16* pA0 = A + (size_t)(m0 + sr) * K + scs;        // rows 0..127
    const hbf16* pA1 = A + (size_t)(m0 + 128 + sr) * K + scs;  // rows 128..255
    const hbf16* pB = Bt + (size_t)(n0 + sr) * K + scs;        // rows 0..127
    __bf16* lA0 = As + tid * 8;          // bytes [0, 8192)
    __bf16* lA1 = As + 4096 + tid * 8;   // bytes [8192, 16384)
    __bf16* lB = Bs + tid * 8;           // bytes [0, 8192)

    int lr = l & 15, lg = l >> 4;
    int ksl = (lg ^ (lr & 3)) * 8;
    int aoff[4], boff[4];
#pragma unroll
    for (int m = 0; m < 4; m++) aoff[m] = (wr * 64 + m * 16 + lr) * 32 + ksl;
#pragma unroll
    for (int n = 0; n < 4; n++) boff[n] = (wc * 64 + n * 16 + lr) * 32 + ksl;

    f32x4 acc[4][4] = {};

    for (int k0 = 0; k0 < K; k0 += 32) {
        GLD16(pA0, lA0);
        GLD16(pA1, lA1);
        GLD16(pB, lB);
        pA0 += 32; pA1 += 32; pB += 32;
        __syncthreads();
        bf16x8 af[4], bfr[4];
#pragma unroll
        for (int m = 0; m < 4; m++) af[m] = *(const bf16x8*)&As[aoff[m]];
#pragma unroll
        for (int n = 0; n < 4; n++) bfr[n] = *(const bf16x8*)&Bs[boff[n]];
#pragma unroll
        for (int m = 0; m < 4; m++)
#pragma unroll
            for (int n = 0; n < 4; n++)
                acc[m][n] = __builtin_amdgcn_mfma_f32_16x16x32_bf16(af[m], bfr[n], acc[m][n], 0, 0, 0);
        __syncthreads();
    }

#pragma unroll
    for (int n = 0; n < 4; n++) {
        int col = n0 + wc * 64 + n * 16 + lr;
        if (col >= N) continue;
#pragma unroll
        for (int m = 0; m < 4; m++) {
#pragma unroll
            for (int r = 0; r < 4; r++) {
                int row = m0 + wr * 64 + m * 16 + lg * 4 + r;
                Cout[(size_t)row * N + col] = acc[m][n][r];
            }
        }
    }
}

// ---------------- MFMA flash attention ----------------
__global__ __launch_bounds__(256) void fattn_kernel(const hbf16* __restrict__ qkv,
                                                    hbf16* __restrict__ y) {
    int qt = gridDim.x - 1 - blockIdx.x;  // heavy tiles first
    int h = blockIdx.y, b = blockIdx.z;
    int q0 = qt * 64;
    int tid = threadIdx.x;
    int l = tid & 63, w = tid >> 6;
    int li = l & 15, lg = l >> 4;
    constexpr int RS = 3 * Dc;
    constexpr int PST = 72;
    constexpr int VST = 72;

    __shared__ __bf16 P_lds[4][16 * PST];
    __shared__ __bf16 Vt[64 * VST];

    bf16x8 qf[2];
    {
        const hbf16* qp = qkv + (size_t)(b * Tc + q0 + w * 16 + li) * RS + h * HDc + lg * 8;
        qf[0] = *(const bf16x8*)qp;
        qf[1] = *(const bf16x8*)(qp + 32);
    }

    f32x4 acc_o[4] = {};
    float m_run[4], l_run[4];
#pragma unroll
    for (int r = 0; r < 4; r++) { m_run[r] = -1e30f; l_run[r] = 0.f; }

    for (int jt = 0; jt <= qt; jt++) {
        int j0 = jt * 64;
        {
            int j = tid >> 2;
            int dbase = (tid & 3) * 16;
            const hbf16* vp = qkv + (size_t)(b * Tc + j0 + j) * RS + 2 * Dc + h * HDc + dbase;
            bf16x8 v0 = *(const bf16x8*)vp;
            bf16x8 v1 = *(const bf16x8*)(vp + 8);
#pragma unroll
            for (int i = 0; i < 8; i++) Vt[(dbase + i) * VST + j] = v0[i];
#pragma unroll
            for (int i = 0; i < 8; i++) Vt[(dbase + 8 + i) * VST + j] = v1[i];
        }

        f32x4 s[4] = {};
#pragma unroll
        for (int ks = 0; ks < 2; ks++) {
#pragma unroll
            for (int n = 0; n < 4; n++) {
                const hbf16* kp = qkv + (size_t)(b * Tc + j0 + n * 16 + li) * RS + Dc + h * HDc + ks * 32 + lg * 8;
                bf16x8 kf = *(const bf16x8*)kp;
                s[n] = __builtin_amdgcn_mfma_f32_16x16x32_bf16(qf[ks], kf, s[n], 0, 0, 0);
            }
        }
#pragma unroll
        for (int n = 0; n < 4; n++)
#pragma unroll
            for (int r = 0; r < 4; r++) s[n][r] *= 0.125f;

        if (jt == qt) {
            int qloc = w * 16 + lg * 4;
#pragma unroll
            for (int n = 0; n < 4; n++) {
                int jloc = n * 16 + li;
#pragma unroll
                for (int r = 0; r < 4; r++)
                    if (jloc > qloc + r) s[n][r] = -1e30f;
            }
        }

        float mnew[4], scl[4];
#pragma unroll
        for (int r = 0; r < 4; r++) {
            float mx = fmaxf(fmaxf(s[0][r], s[1][r]), fmaxf(s[2][r], s[3][r]));
#pragma unroll
            for (int msk = 1; msk <= 8; msk <<= 1) mx = fmaxf(mx, __shfl_xor(mx, msk, 64));
            mnew[r] = fmaxf(m_run[r], mx);
            scl[r] = expf(m_run[r] - mnew[r]);
            m_run[r] = mnew[r];
        }
        float rs[4] = {0.f, 0.f, 0.f, 0.f};
#pragma unroll
        for (int n = 0; n < 4; n++)
#pragma unroll
            for (int r = 0; r < 4; r++) {
                float p = expf(s[n][r] - mnew[r]);
                s[n][r] = p;
                rs[r] += p;
            }
#pragma unroll
        for (int r = 0; r < 4; r++) {
#pragma unroll
            for (int msk = 1; msk <= 8; msk <<= 1) rs[r] += __shfl_xor(rs[r], msk, 64);
            l_run[r] = l_run[r] * scl[r] + rs[r];
        }

#pragma unroll
        for (int n = 0; n < 4; n++)
#pragma unroll
            for (int r = 0; r < 4; r++) {
                hbf16 t = __float2bfloat16(s[n][r]);
                P_lds[w][(lg * 4 + r) * PST + n * 16 + li] = *(__bf16*)&t;
            }
        bf16x8 pa0 = *(const bf16x8*)&P_lds[w][li * PST + lg * 8];
        bf16x8 pa1 = *(const bf16x8*)&P_lds[w][li * PST + 32 + lg * 8];

#pragma unroll
        for (int n2 = 0; n2 < 4; n2++)
#pragma unroll
            for (int r = 0; r < 4; r++) acc_o[n2][r] *= scl[r];

        __syncthreads();
#pragma unroll
        for (int n2 = 0; n2 < 4; n2++) {
            bf16x8 vf0 = *(const bf16x8*)&Vt[(n2 * 16 + li) * VST + lg * 8];
            bf16x8 vf1 = *(const bf16x8*)&Vt[(n2 * 16 + li) * VST + 32 + lg * 8];
            acc_o[n2] = __builtin_amdgcn_mfma_f32_16x16x32_bf16(pa0, vf0, acc_o[n2], 0, 0, 0);
            acc_o[n2] = __builtin_amdgcn_mfma_f32_16x16x32_bf16(pa1, vf1, acc_o[n2], 0, 0, 0);
        }
        __syncthreads();
    }

#pragma unroll
    for (int r = 0; r < 4; r++) {
        float rcp = 1.f / l_run[r];
        int row = q0 + w * 16 + lg * 4 + r;
#pragma unroll
        for (int n2 = 0; n2 < 4; n2++)
            y[(size_t)(b * Tc + row) * Dc + h * HDc + n2 * 16 + li] =
                __float2bfloat16(acc_o[n2][r] * rcp);
    }
}

extern "C" void kernel_launch(void* const* d_in, const int* in_sizes, int n_in,
                              void* d_out, int out_size, void* d_ws, size_t ws_size,
                              hipStream_t stream) {
    const int* x = (const int*)d_in[0];
    const float* wte = (const float*)d_in[1];
    const float* wpe = (const float*)d_in[2];
    const float* ln1w = (const float*)d_in[3];
    const float* ln1b = (const float*)d_in[4];
    const float* qkvw = (const float*)d_in[5];
    const float* qkvb = (const float*)d_in[6];
    const float* projw = (const float*)d_in[7];
    const float* projb = (const float*)d_in[8];
    const float* ln2w = (const float*)d_in[9];
    const float* ln2b = (const float*)d_in[10];
    const float* fcw = (const float*)d_in[11];
    const float* fcb = (const float*)d_in[12];
    const float* fcpw = (const float*)d_in[13];
    const float* fcpb = (const float*)d_in[14];
    const float* lnfw = (const float*)d_in[15];
    const float* lnfb = (const float*)d_in[16];

    char* p = (char*)d_ws;
    float* h = (float*)p;     p += (size_t)Mc * Dc * 4;      // f32 [M][D]
    hbf16* qkv = (hbf16*)p;   p += (size_t)Mc * 3 * Dc * 2;  // bf16 [M][3D]
    hbf16* a = (hbf16*)p;     p += (size_t)Mc * Dc * 2;      // bf16 [M][D]
    hbf16* y = (hbf16*)p;     p += (size_t)Mc * Dc * 2;      // bf16 [M][D]
    hbf16* mlp = (hbf16*)p;   p += (size_t)Mc * 4 * Dc * 2;  // bf16 [M][4D]
    hbf16* wq_t = (hbf16*)p;  p += (size_t)3 * Dc * Dc * 2;
    hbf16* wp_t = (hbf16*)p;  p += (size_t)Dc * Dc * 2;
    hbf16* wf_t = (hbf16*)p;  p += (size_t)4 * Dc * Dc * 2;
    hbf16* wfp_t = (hbf16*)p; p += (size_t)4 * Dc * Dc * 2;
    hbf16* wte_b = (hbf16*)p; p += (size_t)Vpad * Dc * 2;

    embed_kernel<<<(Mc * Dc + 255) / 256, 256, 0, stream>>>(x, wte, wpe, h);
    convert_wte<<<((size_t)Vpad * Dc / 4 + 255) / 256, 256, 0, stream>>>(wte, wte_b);

    for (int l = 0; l < Lc; l++) {
        transpose4_kernel<<<6912, 256, 0, stream>>>(
            qkvw + (size_t)l * Dc * 3 * Dc, projw + (size_t)l * Dc * Dc,
            fcw + (size_t)l * Dc * 4 * Dc, fcpw + (size_t)l * 4 * Dc * Dc,
            wq_t, wp_t, wf_t, wfp_t);

        ln_kernel<<<Mc / 4, 256, 0, stream>>>(h, ln1w + (size_t)l * Dc, ln1b + (size_t)l * Dc, a);
        mm_kernel<0, true, 128><<<dim3(3 * Dc / 128, Mc / 128), 256, 0, stream>>>(
            a, wq_t, qkvb + (size_t)l * 3 * Dc, nullptr, qkv, Mc, 3 * Dc, Dc);
        fattn_kernel<<<dim3(Tc / 64, Hc, Bc), 256, 0, stream>>>(qkv, y);
        mm_kernel<1, false, 64><<<dim3(Dc / 64, Mc / 128), 256, 0, stream>>>(
            y, wp_t, projb + (size_t)l * Dc, h, h, Mc, Dc, Dc);
        ln_kernel<<<Mc / 4, 256, 0, stream>>>(h, ln2w + (size_t)l * Dc, ln2b + (size_t)l * Dc, a);
        mm_kernel<2, true, 128><<<dim3(4 * Dc / 128, Mc / 128), 256, 0, stream>>>(
            a, wf_t, fcb + (size_t)l * 4 * Dc, nullptr, mlp, Mc, 4 * Dc, Dc);
        mm_kernel<1, false, 64><<<dim3(Dc / 64, Mc / 128), 256, 0, stream>>>(
            mlp, wfp_t, fcpb + (size_t)l * Dc, h, h, Mc, Dc, 4 * Dc);
    }

    ln_kernel<<<Mc / 4, 256, 0, stream>>>(h, lnfw, lnfb, a);
    mm2_kernel<<<dim3(Vpad / 128, Mc / 256), 512, 0, stream>>>(
        a, wte_b, (float*)d_out, Mc, Vc, Dc);
}